// Round 15
// baseline (164.287 us; speedup 1.0000x reference)
//
#include <hip/hip_runtime.h>
#include <hip/hip_bf16.h>

// Problem constants
#define BWIN 96      // b*gx*gy = 2*6*8
#define NTOK 320     // l*w1*w2 = 5*8*8
#define DIMX 256
#define HEADS 8
#define DH 32
#define INNER 256
#define CTXW 2560    // HEADS*NTOK
#define MPAD 328     // padded m-stride (bf16) for P/ctx/VW LDS rows
#define ROWS_T 30720 // BWIN*NTOK

typedef __bf16 bf16x8 __attribute__((ext_vector_type(8)));
typedef __bf16 bf16x4 __attribute__((ext_vector_type(4)));
typedef float f32x4 __attribute__((ext_vector_type(4)));

// ---------------- Kernel 1: fused weight-cast + LayerNorm ----------------
__global__ __launch_bounds__(256) void k_pre(
    const float* __restrict__ wq, const float* __restrict__ wkv,
    const float* __restrict__ x, const float* __restrict__ g,
    const float* __restrict__ bt, __bf16* __restrict__ wT,
    __bf16* __restrict__ y)
{
    const int t = threadIdx.x;
    if (blockIdx.x < 768) {
        const int col = blockIdx.x;
        float v;
        if (col < 256)      v = wq[t * 256 + col];
        else if (col < 512) v = wkv[t * 512 + (col - 256)];
        else                v = wkv[t * 512 + 256 + (col - 512)];
        wT[(size_t)col * 256 + t] = (__bf16)v;
        return;
    }
    const int wave = t >> 6, lane = t & 63;
    const int row = (blockIdx.x - 768) * 4 + wave;
    const int bb = row / NTOK, n = row % NTOK;
    const int b_idx = bb / 48, x_idx = (bb % 48) >> 3, y_idx = bb & 7;
    const int l_idx = n >> 6, w1_idx = (n >> 3) & 7, w2_idx = n & 7;
    const size_t src =
        ((((((size_t)b_idx * 5 + l_idx) * 6 + x_idx) * 8 + y_idx) * 8 + w1_idx) * 8 + w2_idx) * (size_t)DIMX;

    const float4 xv = *(const float4*)(x + src + lane * 4);
    float s = xv.x + xv.y + xv.z + xv.w;
    float ss = xv.x * xv.x + xv.y * xv.y + xv.z * xv.z + xv.w * xv.w;
    #pragma unroll
    for (int o = 32; o > 0; o >>= 1) {
        s += __shfl_xor(s, o);
        ss += __shfl_xor(ss, o);
    }
    const float mu = s * (1.0f / DIMX);
    const float var = ss * (1.0f / DIMX) - mu * mu;
    const float rsig = rsqrtf(var + 1e-5f);
    const float4 g4 = *(const float4*)(g + lane * 4);
    const float4 b4 = *(const float4*)(bt + lane * 4);
    bf16x4 yo;
    yo[0] = (__bf16)((xv.x - mu) * rsig * g4.x + b4.x);
    yo[1] = (__bf16)((xv.y - mu) * rsig * g4.y + b4.y);
    yo[2] = (__bf16)((xv.z - mu) * rsig * g4.z + b4.z);
    yo[3] = (__bf16)((xv.w - mu) * rsig * g4.w + b4.w);
    *(bf16x4*)(y + (size_t)row * DIMX + lane * 4) = yo;
}

// ---------------- Kernel 2: QKV GEMM, XCD-bijective swizzle ----------------
__global__ __launch_bounds__(256) void k_qkv(
    const __bf16* __restrict__ y, const __bf16* __restrict__ wT,
    __bf16* __restrict__ qhb, __bf16* __restrict__ khb, __bf16* __restrict__ vhb)
{
    __shared__ __bf16 yls[128][40];
    __shared__ __bf16 wls[128][40];
    const int t = threadIdx.x, wave = t >> 6, lane = t & 63;
    const int lr = lane & 15, lg = lane >> 4;
    const int wm = wave & 1, wn = wave >> 1;
    const int bid = blockIdx.x;
    const int l2 = (bid & 7) * 180 + (bid >> 3);   // bijective (1440 % 8 == 0)
    const int rbase = (l2 / 6) * 128;
    const int cbase = (l2 % 6) * 128;

    f32x4 acc[4][4];
    #pragma unroll
    for (int im = 0; im < 4; ++im)
        #pragma unroll
        for (int jn = 0; jn < 4; ++jn) acc[im][jn] = (f32x4){0.f, 0.f, 0.f, 0.f};

    const int srow = t >> 1, sseg = (t & 1) * 16;
    #pragma unroll
    for (int ks = 0; ks < 8; ++ks) {
        __syncthreads();
        #pragma unroll
        for (int j = 0; j < 2; ++j) {
            *(bf16x8*)&yls[srow][sseg + j * 8] =
                *(const bf16x8*)(y + (size_t)(rbase + srow) * DIMX + ks * 32 + sseg + j * 8);
            *(bf16x8*)&wls[srow][sseg + j * 8] =
                *(const bf16x8*)(wT + (size_t)(cbase + srow) * DIMX + ks * 32 + sseg + j * 8);
        }
        __syncthreads();

        bf16x8 yfr[4], wfr[4];
        #pragma unroll
        for (int jn = 0; jn < 4; ++jn) yfr[jn] = *(const bf16x8*)&yls[wm * 64 + jn * 16 + lr][lg * 8];
        #pragma unroll
        for (int im = 0; im < 4; ++im) wfr[im] = *(const bf16x8*)&wls[wn * 64 + im * 16 + lr][lg * 8];
        #pragma unroll
        for (int im = 0; im < 4; ++im)
            #pragma unroll
            for (int jn = 0; jn < 4; ++jn)
                acc[im][jn] = __builtin_amdgcn_mfma_f32_16x16x32_bf16(wfr[im], yfr[jn], acc[im][jn], 0, 0, 0);
    }

    #pragma unroll
    for (int im = 0; im < 4; ++im) {
        const int g = cbase + wn * 64 + im * 16 + lg * 4;   // global col 0..767
        const int which = g >> 8;
        __bf16* buf = (which == 0) ? qhb : (which == 1) ? khb : vhb;
        const int hh = (g & 255) >> 5, d = g & 31;
        #pragma unroll
        for (int jn = 0; jn < 4; ++jn) {
            const int row = rbase + wm * 64 + jn * 16 + lr;
            const int bb2 = row / NTOK, n2 = row % NTOK;
            bf16x4 p;
            #pragma unroll
            for (int i = 0; i < 4; ++i) p[i] = (__bf16)acc[im][jn][i];
            *(bf16x4*)(buf + ((size_t)(bb2 * 8 + hh) * NTOK + n2) * DH + d) = p;
        }
    }
}

// ---------------- Kernel 3: fused VW + attention, half-panel blocks ----------------
// grid (1536) = (bb, h, half); 256 thr = 4 waves. Exactly 3 dispatch rounds at
// 2 blocks/CU -> ~100% CU utilization (768-block version idled half the chip
// during its second round). No block barriers in the main loop, so waves take
// UNEQUAL tile counts: w0:{0,4,8} w1:{1,5,9} w2:{2,6} w3:{3,7} within the half.
// VW^T prologue duplicated per half (40 extra MFMAs/panel -- MfmaUtil is 2%).
__global__ __launch_bounds__(256) void k_attn(
    const __bf16* __restrict__ qhb, const __bf16* __restrict__ khb,
    const __bf16* __restrict__ vhb, const float* __restrict__ wout,
    const float* __restrict__ ctx, float* __restrict__ part)
{
    __shared__ __bf16 vwls[DH][MPAD];       // 20,992 B
    __shared__ __bf16 ctxls[4][16][MPAD];   // 41,984 B (per-wave; P aliases)
    const int t = threadIdx.x, wave = t >> 6, lane = t & 63;
    const int lr = lane & 15, lg = lane >> 4;
    const int half = blockIdx.x & 1;
    const int h = (blockIdx.x >> 1) & 7;
    const int bb = blockIdx.x >> 4;
    const size_t panel = (size_t)(bb * 8 + h);

    // --- compute VW^T into LDS: wave covers m = wave*80 .. +79 (5 mt) ---
    {
        bf16x8 afr[2];
        #pragma unroll
        for (int rt = 0; rt < 2; ++rt)
            #pragma unroll
            for (int j = 0; j < 8; ++j)
                afr[rt][j] = (__bf16)wout[(h * 32 + lg * 8 + j) * 32 + rt * 16 + lr];
        const __bf16* vbase = vhb + panel * NTOK * DH + lg * 8;
        #pragma unroll
        for (int mt = 0; mt < 5; ++mt) {
            const int m = wave * 80 + mt * 16 + lr;
            const bf16x8 bfr = *(const bf16x8*)(vbase + (size_t)m * DH);
            #pragma unroll
            for (int rt = 0; rt < 2; ++rt) {
                const f32x4 d4 = __builtin_amdgcn_mfma_f32_16x16x32_bf16(
                    afr[rt], bfr, (f32x4){0.f, 0.f, 0.f, 0.f}, 0, 0, 0);
                #pragma unroll
                for (int i = 0; i < 4; ++i)
                    vwls[rt * 16 + lg * 4 + i][wave * 80 + mt * 16 + lr] = (__bf16)d4[i];
            }
        }
    }
    __syncthreads();

    const float* cpan = ctx + (size_t)bb * NTOK * CTXW + h * NTOK;
    const __bf16* qpan = qhb + panel * NTOK * DH;
    const __bf16* kpan = khb + panel * NTOK * DH;
    float* ppan = part + ((size_t)h * ROWS_T + (size_t)bb * NTOK) * DH;

    // wave's tile list within this half: tile(i) = half*10 + wave + 4*i
    const int cnt = (wave < 2) ? 3 : 2;

    // prologue: prefetch ctx tile for i = 0
    float4 creg[20];
    {
        const float* cb = cpan + (size_t)((half * 10 + wave) * 16) * CTXW;
        #pragma unroll
        for (int j = 0; j < 20; ++j) {
            const int f = j * 64 + lane, r = f / 80, c = f % 80;
            creg[j] = *(const float4*)(cb + (size_t)r * CTXW + c * 4);
        }
    }

    for (int i = 0; i < cnt; ++i) {
        const int tile = half * 10 + wave + 4 * i;
        const int nw = tile * 16;

        // write current ctx regs -> LDS (bf16)
        #pragma unroll
        for (int j = 0; j < 20; ++j) {
            const int f = j * 64 + lane, r = f / 80, c = f % 80;
            bf16x4 b;
            b[0] = (__bf16)creg[j].x; b[1] = (__bf16)creg[j].y;
            b[2] = (__bf16)creg[j].z; b[3] = (__bf16)creg[j].w;
            *(bf16x4*)&ctxls[wave][r][c * 4] = b;
        }
        // prefetch next tile (overlaps the whole iteration below)
        if (i + 1 < cnt) {
            const float* cb = cpan + (size_t)((tile + 4) * 16) * CTXW;
            #pragma unroll
            for (int j = 0; j < 20; ++j) {
                const int f = j * 64 + lane, r = f / 80, c = f % 80;
                creg[j] = *(const float4*)(cb + (size_t)r * CTXW + c * 4);
            }
        }

        // Q fragment (head-major)
        const bf16x8 qfrag = *(const bf16x8*)(qpan + (size_t)(nw + lr) * DH + lg * 8);

        // S^T = mfma(K, Q); K fragments from L1/L2-resident global panel
        f32x4 s[20];
        #pragma unroll
        for (int mt = 0; mt < 20; ++mt) {
            const bf16x8 kfrag = *(const bf16x8*)(kpan + (size_t)(mt * 16 + lr) * DH + lg * 8);
            s[mt] = __builtin_amdgcn_mfma_f32_16x16x32_bf16(kfrag, qfrag,
                                                            (f32x4){0.f, 0.f, 0.f, 0.f}, 0, 0, 0);
        }

        // bias add from this wave's ctx slice
        #pragma unroll
        for (int mt = 0; mt < 20; ++mt) {
            const bf16x4 c4 = *(const bf16x4*)&ctxls[wave][lr][mt * 16 + lg * 4];
            #pragma unroll
            for (int i2 = 0; i2 < 4; ++i2) s[mt][i2] += (float)c4[i2];
        }

        // softmax stats
        float mx = -3e38f;
        #pragma unroll
        for (int mt = 0; mt < 20; ++mt)
            #pragma unroll
            for (int i2 = 0; i2 < 4; ++i2) mx = fmaxf(mx, s[mt][i2]);
        mx = fmaxf(mx, __shfl_xor(mx, 16));
        mx = fmaxf(mx, __shfl_xor(mx, 32));

        // exp -> bf16 P over the dead ctx slice (wave-lockstep, no barrier)
        float sum = 0.f;
        #pragma unroll
        for (int mt = 0; mt < 20; ++mt) {
            bf16x4 p4;
            #pragma unroll
            for (int i2 = 0; i2 < 4; ++i2) {
                const float e = __expf(s[mt][i2] - mx);
                sum += e;
                p4[i2] = (__bf16)e;
            }
            *(bf16x4*)&ctxls[wave][lr][mt * 16 + lg * 4] = p4;
        }
        sum += __shfl_xor(sum, 16);
        sum += __shfl_xor(sum, 32);
        const float rinv = 1.0f / sum;

        // O^T += VW^T x P^T from LDS
        f32x4 o0 = {0.f, 0.f, 0.f, 0.f}, o1 = {0.f, 0.f, 0.f, 0.f};
        #pragma unroll
        for (int ks = 0; ks < 10; ++ks) {
            const bf16x8 pfrag = *(const bf16x8*)&ctxls[wave][lr][ks * 32 + lg * 8];
            const bf16x8 vf0 = *(const bf16x8*)&vwls[lr][ks * 32 + lg * 8];
            const bf16x8 vf1 = *(const bf16x8*)&vwls[16 + lr][ks * 32 + lg * 8];
            o0 = __builtin_amdgcn_mfma_f32_16x16x32_bf16(vf0, pfrag, o0, 0, 0, 0);
            o1 = __builtin_amdgcn_mfma_f32_16x16x32_bf16(vf1, pfrag, o1, 0, 0, 0);
        }

        // per-head partial (normalized)
        float* pdst = ppan + (size_t)(nw + lr) * DH + lg * 4;
        f32x4 r0, r1;
        #pragma unroll
        for (int i2 = 0; i2 < 4; ++i2) { r0[i2] = o0[i2] * rinv; r1[i2] = o1[i2] * rinv; }
        *(f32x4*)(pdst)      = r0;
        *(f32x4*)(pdst + 16) = r1;
    }
}

// ---------------- Kernel 4: 8-head reduce + output scatter ----------------
__global__ __launch_bounds__(256) void k_red(
    const float* __restrict__ part, float* __restrict__ out)
{
    const int idx = blockIdx.x * 256 + threadIdx.x;   // ROWS_T*8 total
    const int row = idx >> 3, q4 = (idx & 7) * 4;
    f32x4 a = {0.f, 0.f, 0.f, 0.f};
    #pragma unroll
    for (int h = 0; h < HEADS; ++h) {
        const f32x4 p = *(const f32x4*)(part + ((size_t)h * ROWS_T + row) * DH + q4);
        #pragma unroll
        for (int i = 0; i < 4; ++i) a[i] += p[i];
    }
    const int bb = row / NTOK, n = row % NTOK;
    const int b_idx = bb / 48, x_idx = (bb % 48) >> 3, y_idx = bb & 7;
    const int l_idx = n >> 6, w1_idx = (n >> 3) & 7, w2_idx = n & 7;
    const size_t dst =
        ((((((size_t)b_idx * 5 + l_idx) * 6 + x_idx) * 8 + y_idx) * 8 + w1_idx) * 8 + w2_idx) * (size_t)DH;
    *(f32x4*)(out + dst + q4) = a;
}

extern "C" void kernel_launch(void* const* d_in, const int* in_sizes, int n_in,
                              void* d_out, int out_size, void* d_ws, size_t ws_size,
                              hipStream_t stream) {
    const float* x    = (const float*)d_in[0];
    const float* ctx  = (const float*)d_in[1];
    const float* wq   = (const float*)d_in[2];
    const float* wkv  = (const float*)d_in[3];
    const float* wout = (const float*)d_in[4];
    const float* ln_g = (const float*)d_in[5];
    const float* ln_b = (const float*)d_in[6];
    float* out = (float*)d_out;

    // workspace: qhb|khb|vhb|yb bf16 (SEG each), wT bf16, part f32 (8*ROWS*32)
    const size_t SEG = (size_t)BWIN * NTOK * INNER;  // 7,864,320 elements
    __bf16* qhb = (__bf16*)d_ws;
    __bf16* khb = qhb + SEG;
    __bf16* vhb = khb + SEG;
    __bf16* yb  = vhb + SEG;
    __bf16* wT  = yb + SEG;
    float*  part = (float*)(wT + 768 * 256);

    const int ROWS = BWIN * NTOK;  // 30720
    k_pre<<<768 + ROWS / 4, 256, 0, stream>>>(wq, wkv, x, ln_g, ln_b, wT, yb);
    k_qkv<<<1440, 256, 0, stream>>>(yb, wT, qhb, khb, vhb);
    k_attn<<<BWIN * HEADS * 2, 256, 0, stream>>>(qhb, khb, vhb, wout, ctx, part);
    k_red<<<ROWS * 8 / 256, 256, 0, stream>>>(part, out);
}

// Round 16
// 142.838 us; speedup vs baseline: 1.1502x; 1.1502x over previous
//
#include <hip/hip_runtime.h>
#include <hip/hip_bf16.h>

// Problem constants
#define BWIN 96      // b*gx*gy = 2*6*8
#define NTOK 320     // l*w1*w2 = 5*8*8
#define DIMX 256
#define HEADS 8
#define DH 32
#define INNER 256
#define CTXW 2560    // HEADS*NTOK
#define MPAD 328     // padded m-stride (bf16) for P/ctx/VW LDS rows
#define ROWS_T 30720 // BWIN*NTOK

typedef __bf16 bf16x8 __attribute__((ext_vector_type(8)));
typedef __bf16 bf16x4 __attribute__((ext_vector_type(4)));
typedef float f32x4 __attribute__((ext_vector_type(4)));

// ---------------- Kernel 1: fused weight-cast + LayerNorm ----------------
__global__ __launch_bounds__(256) void k_pre(
    const float* __restrict__ wq, const float* __restrict__ wkv,
    const float* __restrict__ x, const float* __restrict__ g,
    const float* __restrict__ bt, __bf16* __restrict__ wT,
    __bf16* __restrict__ y)
{
    const int t = threadIdx.x;
    if (blockIdx.x < 768) {
        const int col = blockIdx.x;
        float v;
        if (col < 256)      v = wq[t * 256 + col];
        else if (col < 512) v = wkv[t * 512 + (col - 256)];
        else                v = wkv[t * 512 + 256 + (col - 512)];
        wT[(size_t)col * 256 + t] = (__bf16)v;
        return;
    }
    const int wave = t >> 6, lane = t & 63;
    const int row = (blockIdx.x - 768) * 4 + wave;
    const int bb = row / NTOK, n = row % NTOK;
    const int b_idx = bb / 48, x_idx = (bb % 48) >> 3, y_idx = bb & 7;
    const int l_idx = n >> 6, w1_idx = (n >> 3) & 7, w2_idx = n & 7;
    const size_t src =
        ((((((size_t)b_idx * 5 + l_idx) * 6 + x_idx) * 8 + y_idx) * 8 + w1_idx) * 8 + w2_idx) * (size_t)DIMX;

    const float4 xv = *(const float4*)(x + src + lane * 4);
    float s = xv.x + xv.y + xv.z + xv.w;
    float ss = xv.x * xv.x + xv.y * xv.y + xv.z * xv.z + xv.w * xv.w;
    #pragma unroll
    for (int o = 32; o > 0; o >>= 1) {
        s += __shfl_xor(s, o);
        ss += __shfl_xor(ss, o);
    }
    const float mu = s * (1.0f / DIMX);
    const float var = ss * (1.0f / DIMX) - mu * mu;
    const float rsig = rsqrtf(var + 1e-5f);
    const float4 g4 = *(const float4*)(g + lane * 4);
    const float4 b4 = *(const float4*)(bt + lane * 4);
    bf16x4 yo;
    yo[0] = (__bf16)((xv.x - mu) * rsig * g4.x + b4.x);
    yo[1] = (__bf16)((xv.y - mu) * rsig * g4.y + b4.y);
    yo[2] = (__bf16)((xv.z - mu) * rsig * g4.z + b4.z);
    yo[3] = (__bf16)((xv.w - mu) * rsig * g4.w + b4.w);
    *(bf16x4*)(y + (size_t)row * DIMX + lane * 4) = yo;
}

// ---------------- Kernel 2: QKV GEMM, XCD-bijective swizzle ----------------
__global__ __launch_bounds__(256) void k_qkv(
    const __bf16* __restrict__ y, const __bf16* __restrict__ wT,
    __bf16* __restrict__ qhb, __bf16* __restrict__ khb, __bf16* __restrict__ vhb)
{
    __shared__ __bf16 yls[128][40];
    __shared__ __bf16 wls[128][40];
    const int t = threadIdx.x, wave = t >> 6, lane = t & 63;
    const int lr = lane & 15, lg = lane >> 4;
    const int wm = wave & 1, wn = wave >> 1;
    const int bid = blockIdx.x;
    const int l2 = (bid & 7) * 180 + (bid >> 3);   // bijective (1440 % 8 == 0)
    const int rbase = (l2 / 6) * 128;
    const int cbase = (l2 % 6) * 128;

    f32x4 acc[4][4];
    #pragma unroll
    for (int im = 0; im < 4; ++im)
        #pragma unroll
        for (int jn = 0; jn < 4; ++jn) acc[im][jn] = (f32x4){0.f, 0.f, 0.f, 0.f};

    const int srow = t >> 1, sseg = (t & 1) * 16;
    #pragma unroll
    for (int ks = 0; ks < 8; ++ks) {
        __syncthreads();
        #pragma unroll
        for (int j = 0; j < 2; ++j) {
            *(bf16x8*)&yls[srow][sseg + j * 8] =
                *(const bf16x8*)(y + (size_t)(rbase + srow) * DIMX + ks * 32 + sseg + j * 8);
            *(bf16x8*)&wls[srow][sseg + j * 8] =
                *(const bf16x8*)(wT + (size_t)(cbase + srow) * DIMX + ks * 32 + sseg + j * 8);
        }
        __syncthreads();

        bf16x8 yfr[4], wfr[4];
        #pragma unroll
        for (int jn = 0; jn < 4; ++jn) yfr[jn] = *(const bf16x8*)&yls[wm * 64 + jn * 16 + lr][lg * 8];
        #pragma unroll
        for (int im = 0; im < 4; ++im) wfr[im] = *(const bf16x8*)&wls[wn * 64 + im * 16 + lr][lg * 8];
        #pragma unroll
        for (int im = 0; im < 4; ++im)
            #pragma unroll
            for (int jn = 0; jn < 4; ++jn)
                acc[im][jn] = __builtin_amdgcn_mfma_f32_16x16x32_bf16(wfr[im], yfr[jn], acc[im][jn], 0, 0, 0);
    }

    #pragma unroll
    for (int im = 0; im < 4; ++im) {
        const int g = cbase + wn * 64 + im * 16 + lg * 4;   // global col 0..767
        const int which = g >> 8;
        __bf16* buf = (which == 0) ? qhb : (which == 1) ? khb : vhb;
        const int hh = (g & 255) >> 5, d = g & 31;
        #pragma unroll
        for (int jn = 0; jn < 4; ++jn) {
            const int row = rbase + wm * 64 + jn * 16 + lr;
            const int bb2 = row / NTOK, n2 = row % NTOK;
            bf16x4 p;
            #pragma unroll
            for (int i = 0; i < 4; ++i) p[i] = (__bf16)acc[im][jn][i];
            *(bf16x4*)(buf + ((size_t)(bb2 * 8 + hh) * NTOK + n2) * DH + d) = p;
        }
    }
}

// ---------------- Kernel 3: fused VW + attention, 4 waves/block (R14 config) ----------------
// grid (768) = (bb, h), h fastest; 256 thr = 4 waves; wave w handles q-tiles
// it*4+w (5 iterations -- the even 20/4 split; R15's half-panel 10/4 split
// regressed 17us from 3,3,2,2 imbalance + duplicated prologues).
// part stored in bf16 (halves the 63MB round-trip; partials are O(1) convex
// combos -> rounding adds <=~0.004 over 8 heads, within threshold budget).
__global__ __launch_bounds__(256) void k_attn(
    const __bf16* __restrict__ qhb, const __bf16* __restrict__ khb,
    const __bf16* __restrict__ vhb, const float* __restrict__ wout,
    const float* __restrict__ ctx, __bf16* __restrict__ part)
{
    __shared__ __bf16 vwls[DH][MPAD];       // 20,992 B
    __shared__ __bf16 ctxls[4][16][MPAD];   // 41,984 B (per-wave; P aliases)
    const int t = threadIdx.x, wave = t >> 6, lane = t & 63;
    const int lr = lane & 15, lg = lane >> 4;
    const int h = blockIdx.x & 7, bb = blockIdx.x >> 3;
    const size_t panel = (size_t)(bb * 8 + h);

    // --- compute VW^T into LDS: wave covers m = wave*80 .. +79 (5 mt) ---
    {
        bf16x8 afr[2];
        #pragma unroll
        for (int rt = 0; rt < 2; ++rt)
            #pragma unroll
            for (int j = 0; j < 8; ++j)
                afr[rt][j] = (__bf16)wout[(h * 32 + lg * 8 + j) * 32 + rt * 16 + lr];
        const __bf16* vbase = vhb + panel * NTOK * DH + lg * 8;
        #pragma unroll
        for (int mt = 0; mt < 5; ++mt) {
            const int m = wave * 80 + mt * 16 + lr;
            const bf16x8 bfr = *(const bf16x8*)(vbase + (size_t)m * DH);
            #pragma unroll
            for (int rt = 0; rt < 2; ++rt) {
                const f32x4 d4 = __builtin_amdgcn_mfma_f32_16x16x32_bf16(
                    afr[rt], bfr, (f32x4){0.f, 0.f, 0.f, 0.f}, 0, 0, 0);
                #pragma unroll
                for (int i = 0; i < 4; ++i)
                    vwls[rt * 16 + lg * 4 + i][wave * 80 + mt * 16 + lr] = (__bf16)d4[i];
            }
        }
    }
    __syncthreads();

    const float* cpan = ctx + (size_t)bb * NTOK * CTXW + h * NTOK;
    const __bf16* qpan = qhb + panel * NTOK * DH;
    const __bf16* kpan = khb + panel * NTOK * DH;
    __bf16* ppan = part + ((size_t)h * ROWS_T + (size_t)bb * NTOK) * DH;

    // prologue: prefetch ctx tile for iteration 0 (wave's q-tile = 4*it + wave)
    float4 creg[20];
    {
        const float* cb = cpan + (size_t)(wave * 16) * CTXW;
        #pragma unroll
        for (int j = 0; j < 20; ++j) {
            const int f = j * 64 + lane, r = f / 80, c = f % 80;
            creg[j] = *(const float4*)(cb + (size_t)r * CTXW + c * 4);
        }
    }

    for (int it = 0; it < 5; ++it) {
        const int nw = (it * 4 + wave) * 16;

        // write current ctx regs -> LDS (bf16)
        #pragma unroll
        for (int j = 0; j < 20; ++j) {
            const int f = j * 64 + lane, r = f / 80, c = f % 80;
            bf16x4 b;
            b[0] = (__bf16)creg[j].x; b[1] = (__bf16)creg[j].y;
            b[2] = (__bf16)creg[j].z; b[3] = (__bf16)creg[j].w;
            *(bf16x4*)&ctxls[wave][r][c * 4] = b;
        }
        // prefetch next tile (overlaps the whole iteration below)
        if (it < 4) {
            const float* cb = cpan + (size_t)((it * 4 + 4 + wave) * 16) * CTXW;
            #pragma unroll
            for (int j = 0; j < 20; ++j) {
                const int f = j * 64 + lane, r = f / 80, c = f % 80;
                creg[j] = *(const float4*)(cb + (size_t)r * CTXW + c * 4);
            }
        }

        // Q fragment (head-major)
        const bf16x8 qfrag = *(const bf16x8*)(qpan + (size_t)(nw + lr) * DH + lg * 8);

        // S^T = mfma(K, Q); K fragments from L1-resident global panel
        f32x4 s[20];
        #pragma unroll
        for (int mt = 0; mt < 20; ++mt) {
            const bf16x8 kfrag = *(const bf16x8*)(kpan + (size_t)(mt * 16 + lr) * DH + lg * 8);
            s[mt] = __builtin_amdgcn_mfma_f32_16x16x32_bf16(kfrag, qfrag,
                                                            (f32x4){0.f, 0.f, 0.f, 0.f}, 0, 0, 0);
        }

        // bias add from this wave's ctx slice
        #pragma unroll
        for (int mt = 0; mt < 20; ++mt) {
            const bf16x4 c4 = *(const bf16x4*)&ctxls[wave][lr][mt * 16 + lg * 4];
            #pragma unroll
            for (int i = 0; i < 4; ++i) s[mt][i] += (float)c4[i];
        }

        // softmax stats
        float mx = -3e38f;
        #pragma unroll
        for (int mt = 0; mt < 20; ++mt)
            #pragma unroll
            for (int i = 0; i < 4; ++i) mx = fmaxf(mx, s[mt][i]);
        mx = fmaxf(mx, __shfl_xor(mx, 16));
        mx = fmaxf(mx, __shfl_xor(mx, 32));

        // exp -> bf16 P over the dead ctx slice (wave-lockstep, no barrier)
        float sum = 0.f;
        #pragma unroll
        for (int mt = 0; mt < 20; ++mt) {
            bf16x4 p4;
            #pragma unroll
            for (int i = 0; i < 4; ++i) {
                const float e = __expf(s[mt][i] - mx);
                sum += e;
                p4[i] = (__bf16)e;
            }
            *(bf16x4*)&ctxls[wave][lr][mt * 16 + lg * 4] = p4;
        }
        sum += __shfl_xor(sum, 16);
        sum += __shfl_xor(sum, 32);
        const float rinv = 1.0f / sum;

        // O^T += VW^T x P^T from LDS
        f32x4 o0 = {0.f, 0.f, 0.f, 0.f}, o1 = {0.f, 0.f, 0.f, 0.f};
        #pragma unroll
        for (int ks = 0; ks < 10; ++ks) {
            const bf16x8 pfrag = *(const bf16x8*)&ctxls[wave][lr][ks * 32 + lg * 8];
            const bf16x8 vf0 = *(const bf16x8*)&vwls[lr][ks * 32 + lg * 8];
            const bf16x8 vf1 = *(const bf16x8*)&vwls[16 + lr][ks * 32 + lg * 8];
            o0 = __builtin_amdgcn_mfma_f32_16x16x32_bf16(vf0, pfrag, o0, 0, 0, 0);
            o1 = __builtin_amdgcn_mfma_f32_16x16x32_bf16(vf1, pfrag, o1, 0, 0, 0);
        }

        // per-head partial (normalized, bf16)
        __bf16* pdst = ppan + (size_t)(nw + lr) * DH + lg * 4;
        bf16x4 r0, r1;
        #pragma unroll
        for (int i = 0; i < 4; ++i) {
            r0[i] = (__bf16)(o0[i] * rinv);
            r1[i] = (__bf16)(o1[i] * rinv);
        }
        *(bf16x4*)(pdst)      = r0;
        *(bf16x4*)(pdst + 16) = r1;
    }
}

// ---------------- Kernel 4: 8-head reduce + output scatter ----------------
__global__ __launch_bounds__(256) void k_red(
    const __bf16* __restrict__ part, float* __restrict__ out)
{
    const int idx = blockIdx.x * 256 + threadIdx.x;   // ROWS_T*8 total
    const int row = idx >> 3, q4 = (idx & 7) * 4;
    f32x4 a = {0.f, 0.f, 0.f, 0.f};
    #pragma unroll
    for (int h = 0; h < HEADS; ++h) {
        const bf16x4 p = *(const bf16x4*)(part + ((size_t)h * ROWS_T + row) * DH + q4);
        #pragma unroll
        for (int i = 0; i < 4; ++i) a[i] += (float)p[i];
    }
    const int bb = row / NTOK, n = row % NTOK;
    const int b_idx = bb / 48, x_idx = (bb % 48) >> 3, y_idx = bb & 7;
    const int l_idx = n >> 6, w1_idx = (n >> 3) & 7, w2_idx = n & 7;
    const size_t dst =
        ((((((size_t)b_idx * 5 + l_idx) * 6 + x_idx) * 8 + y_idx) * 8 + w1_idx) * 8 + w2_idx) * (size_t)DH;
    *(f32x4*)(out + dst + q4) = a;
}

extern "C" void kernel_launch(void* const* d_in, const int* in_sizes, int n_in,
                              void* d_out, int out_size, void* d_ws, size_t ws_size,
                              hipStream_t stream) {
    const float* x    = (const float*)d_in[0];
    const float* ctx  = (const float*)d_in[1];
    const float* wq   = (const float*)d_in[2];
    const float* wkv  = (const float*)d_in[3];
    const float* wout = (const float*)d_in[4];
    const float* ln_g = (const float*)d_in[5];
    const float* ln_b = (const float*)d_in[6];
    float* out = (float*)d_out;

    // workspace: qhb|khb|vhb|yb bf16 (SEG each), wT bf16, part bf16 (8*ROWS*32)
    const size_t SEG = (size_t)BWIN * NTOK * INNER;  // 7,864,320 elements
    __bf16* qhb = (__bf16*)d_ws;
    __bf16* khb = qhb + SEG;
    __bf16* vhb = khb + SEG;
    __bf16* yb  = vhb + SEG;
    __bf16* wT  = yb + SEG;
    __bf16* part = wT + 768 * 256;

    const int ROWS = BWIN * NTOK;  // 30720
    k_pre<<<768 + ROWS / 4, 256, 0, stream>>>(wq, wkv, x, ln_g, ln_b, wT, yb);
    k_qkv<<<1440, 256, 0, stream>>>(yb, wT, qhb, khb, vhb);
    k_attn<<<BWIN * HEADS, 256, 0, stream>>>(qhb, khb, vhb, wout, ctx, part);
    k_red<<<ROWS * 8 / 256, 256, 0, stream>>>(part, out);
}